// Round 16
// baseline (1486.998 us; speedup 1.0000x reference)
//
#include <hip/hip_runtime.h>
#include <math.h>

#define NIMG 12
#define NN 512
#define NPIX (NN * NN)
#define XST (257 * 512)   // compact Hermitian-half X: cols 0..256, 512 rows

__device__ __forceinline__ int brev9(int p) {
  return (int)(__brev((unsigned)p) >> 23);
}

// ---------------------------------------------------------------------------
// FROZEN 512-pt radix-2 DIT FFT core (f32, no FMA) — bit-identical to R11-R15.
// ---------------------------------------------------------------------------
__device__ __forceinline__ void fft512_core(
    float vr[8], float vi[8], const int inv,
    const float* __restrict__ twr, const float* __restrict__ twi,
    const int lane)
{
#pragma unroll
  for (int s = 0; s < 3; ++s) {
    const int half = 1 << s;
#pragma unroll
    for (int e = 0; e < 8; ++e) {
      if ((e & half) == 0) {
        const int j = (e & (half - 1)) << (8 - s);
        const float wr = twr[j];
        const float wi = inv ? -twi[j] : twi[j];
        const float br = vr[e + half], bi = vi[e + half];
        const float tr = __fsub_rn(__fmul_rn(wr, br), __fmul_rn(wi, bi));
        const float ti = __fadd_rn(__fmul_rn(wr, bi), __fmul_rn(wi, br));
        vr[e + half] = __fsub_rn(vr[e], tr); vi[e + half] = __fsub_rn(vi[e], ti);
        vr[e] = __fadd_rn(vr[e], tr); vi[e] = __fadd_rn(vi[e], ti);
      }
    }
  }
#pragma unroll
  for (int s = 3; s <= 8; ++s) {
    const int xm = 1 << (s - 3);
    const bool low = (lane & xm) == 0;
#pragma unroll
    for (int e = 0; e < 8; ++e) {
      const float orr = __shfl_xor(vr[e], xm);
      const float oii = __shfl_xor(vi[e], xm);
      const int j = ((((lane & (xm - 1)) << 3) | e)) << (8 - s);
      const float wr = twr[j];
      const float wi = inv ? -twi[j] : twi[j];
      if (low) {
        const float tr = __fsub_rn(__fmul_rn(wr, orr), __fmul_rn(wi, oii));
        const float ti = __fadd_rn(__fmul_rn(wr, oii), __fmul_rn(wi, orr));
        vr[e] = __fadd_rn(vr[e], tr); vi[e] = __fadd_rn(vi[e], ti);
      } else {
        const float tr = __fsub_rn(__fmul_rn(wr, vr[e]), __fmul_rn(wi, vi[e]));
        const float ti = __fadd_rn(__fmul_rn(wr, vi[e]), __fmul_rn(wi, vr[e]));
        vr[e] = __fsub_rn(orr, tr); vi[e] = __fsub_rn(oii, ti);
      }
    }
  }
  if (inv) {
    const float sc = 1.0f / 512.0f;
#pragma unroll
    for (int e = 0; e < 8; ++e) {
      vr[e] = __fmul_rn(vr[e], sc); vi[e] = __fmul_rn(vi[e], sc);
    }
  }
}

// numpy pairwise base block (frozen).
__device__ __forceinline__ float np_pw_base(const float* a, int n)
{
  float r0 = a[0], r1 = a[1], r2 = a[2], r3 = a[3];
  float r4 = a[4], r5 = a[5], r6 = a[6], r7 = a[7];
  int i = 8;
  const int lim = n - (n & 7);
  for (; i < lim; i += 8) {
    r0 = __fadd_rn(r0, a[i + 0]); r1 = __fadd_rn(r1, a[i + 1]);
    r2 = __fadd_rn(r2, a[i + 2]); r3 = __fadd_rn(r3, a[i + 3]);
    r4 = __fadd_rn(r4, a[i + 4]); r5 = __fadd_rn(r5, a[i + 5]);
    r6 = __fadd_rn(r6, a[i + 6]); r7 = __fadd_rn(r7, a[i + 7]);
  }
  float res = __fadd_rn(
      __fadd_rn(__fadd_rn(r0, r1), __fadd_rn(r2, r3)),
      __fadd_rn(__fadd_rn(r4, r5), __fadd_rn(r6, r7)));
  for (; i < n; ++i) res = __fadd_rn(res, a[i]);
  return res;
}

// ---------------------------------------------------------------------------
__global__ __launch_bounds__(256) void twiddle_kernel(float2* __restrict__ twg)
{
  const int k = threadIdx.x;
  double s, c;
  sincos(-2.0 * M_PI * (double)k / 512.0, &s, &c);
  twg[k] = make_float2((float)c, (float)s);
}

__global__ __launch_bounds__(256) void loadmag_kernel(
    const float* __restrict__ bx, const float* __restrict__ by,
    const float* __restrict__ lx, const float* __restrict__ ly,
    float2* __restrict__ B2, float2* __restrict__ B1)
{
  const int i = blockIdx.x * 256 + threadIdx.x;
  {
    const float a = lx[i], b = ly[i];
    const float s = __fadd_rn(__fmul_rn(a, a), __fmul_rn(b, b));
    B2[i] = make_float2((float)sqrt((double)s), 0.f);
  }
  {
    const float a = bx[i], b = by[i];
    const float s = __fadd_rn(__fmul_rn(a, a), __fmul_rn(b, b));
    B1[i] = make_float2((float)sqrt((double)s), 0.f);
  }
}

__global__ __launch_bounds__(256) void rowfft_kernel(
    float2* __restrict__ A, float2* __restrict__ B,
    const float2* __restrict__ twg)
{
  __shared__ float twr[256], twi[256];
  { const float2 t = twg[threadIdx.x]; twr[threadIdx.x] = t.x; twi[threadIdx.x] = t.y; }
  __syncthreads();
  int wid = blockIdx.x * 4 + (threadIdx.x >> 6);
  const int lane = threadIdx.x & 63;
  float2* buf = A;
  if (wid >= NIMG * NN) { wid -= NIMG * NN; buf = B; }
  const int base = (wid >> 9) * NPIX + (wid & 511) * NN;
  float vr[8], vi[8];
#pragma unroll
  for (int e = 0; e < 8; ++e) {
    const float2 z = buf[base + brev9(lane * 8 + e)];
    vr[e] = z.x; vi[e] = z.y;
  }
  fft512_core(vr, vi, 0, twr, twi, lane);
#pragma unroll
  for (int e = 0; e < 8; ++e)
    buf[base + lane * 8 + e] = make_float2(vr[e], vi[e]);
}

__global__ __launch_bounds__(256) void colA_kernel(
    float2* __restrict__ B2, const float2* __restrict__ twg)
{
  __shared__ float twr[256], twi[256];
  __shared__ float2 ld[4][520];
  { const float2 t = twg[threadIdx.x]; twr[threadIdx.x] = t.x; twi[threadIdx.x] = t.y; }
  const int img = blockIdx.x >> 7;
  const int c0  = (blockIdx.x & 127) * 4;
  const int tid = threadIdx.x;
  float2* __restrict__ base = B2 + img * NPIX;
  for (int it = 0; it < 8; ++it) {
    const int idx = it * 256 + tid;
    ld[idx & 3][idx >> 2] = base[(idx >> 2) * NN + c0 + (idx & 3)];
  }
  __syncthreads();
  const int w = tid >> 6, lane = tid & 63;
  float vr[8], vi[8];
#pragma unroll
  for (int e = 0; e < 8; ++e) {
    const float2 z = ld[w][brev9(lane * 8 + e)];
    vr[e] = z.x; vi[e] = z.y;
  }
  fft512_core(vr, vi, 0, twr, twi, lane);
#pragma unroll
  for (int e = 0; e < 8; ++e) ld[w][lane * 8 + e] = make_float2(vr[e], vi[e]);
  __syncthreads();
  for (int it = 0; it < 8; ++it) {
    const int idx = it * 256 + tid;
    base[(idx >> 2) * NN + c0 + (idx & 3)] = ld[idx & 3][idx >> 2];
  }
}

// colB: blur col FFTs, COMPACT Hermitian half: cols 0..256 -> XH [c][r].
__global__ __launch_bounds__(256) void colB_kernel(
    const float2* __restrict__ B1, float2* __restrict__ XH,
    const float2* __restrict__ twg)
{
  __shared__ float twr[256], twi[256];
  __shared__ float2 ld[4][520];
  { const float2 t = twg[threadIdx.x]; twr[threadIdx.x] = t.x; twi[threadIdx.x] = t.y; }
  const int img = blockIdx.x / 65;
  const int c0  = (blockIdx.x % 65) * 4;
  const int tid = threadIdx.x;
  const float2* __restrict__ in = B1 + img * NPIX;
  for (int it = 0; it < 8; ++it) {
    const int idx = it * 256 + tid;
    const int cc = c0 + (idx & 3);
    ld[idx & 3][idx >> 2] = in[(idx >> 2) * NN + (cc < NN ? cc : NN - 1)];
  }
  __syncthreads();
  const int w = tid >> 6, lane = tid & 63;
  const int c = c0 + w;
  if (c > 256) return;
  float vr[8], vi[8];
#pragma unroll
  for (int e = 0; e < 8; ++e) {
    const float2 z = ld[w][brev9(lane * 8 + e)];
    vr[e] = z.x; vi[e] = z.y;
  }
  fft512_core(vr, vi, 0, twr, twi, lane);
  float2* __restrict__ out = XH + (size_t)img * XST + c * NN + lane * 8;
#pragma unroll
  for (int e = 0; e < 8; ++e) out[e] = make_float2(vr[e], vi[e]);
}

__global__ __launch_bounds__(256) void fp_kernel(
    const float2* __restrict__ B2, float* __restrict__ FP)
{
  const int i = blockIdx.x * 256 + threadIdx.x;
  const float2 l = B2[i];
  FP[i] = __fadd_rn(__fmul_rn(l.x, l.x), __fmul_rn(l.y, l.y));
}

// kb: APPLY col-FFTs, compact half (cols 0..256) from R; fused mask stats.
// Stats over the stored half equal full-range stats (|Im conj z| = |Im z|).
__global__ __launch_bounds__(256) void kb_kernel(
    const float2* __restrict__ R, float2* __restrict__ XH,
    unsigned* __restrict__ stats, const float2* __restrict__ twg)
{
  __shared__ float twr[256], twi[256];
  __shared__ float smi[4], sma[4];
  { const float2 t = twg[threadIdx.x]; twr[threadIdx.x] = t.x; twi[threadIdx.x] = t.y; }
  __syncthreads();
  const int img = blockIdx.x / 65;
  const int c   = (blockIdx.x % 65) * 4 + (threadIdx.x >> 6);
  const int lane = threadIdx.x & 63;
  float mi = 0.f, ma = 0.f;
  if (c <= 256) {
    float vr[8], vi[8];
#pragma unroll
    for (int e = 0; e < 8; ++e) {
      const int q = brev9(lane * 8 + e);
      const int k = (q + 15) & 511;
      if (k < 31) {
        const float2 z = R[(img * 31 + k) * NN + c];
        vr[e] = z.x; vi[e] = z.y;
      } else { vr[e] = 0.f; vi[e] = 0.f; }
    }
    fft512_core(vr, vi, 0, twr, twi, lane);
#pragma unroll
    for (int e = 0; e < 8; ++e) {
      mi = fmaxf(mi, fabsf(vi[e]));
      const float ab = (float)sqrt(
          (double)__fadd_rn(__fmul_rn(vr[e], vr[e]), __fmul_rn(vi[e], vi[e])));
      ma = fmaxf(ma, ab);
    }
    float2* __restrict__ out = XH + (size_t)img * XST + c * NN + lane * 8;
#pragma unroll
    for (int e = 0; e < 8; ++e) out[e] = make_float2(vr[e], vi[e]);
  }
#pragma unroll
  for (int off = 32; off; off >>= 1) {
    mi = fmaxf(mi, __shfl_xor(mi, off));
    ma = fmaxf(ma, __shfl_xor(ma, off));
  }
  if (lane == 0) { smi[threadIdx.x >> 6] = mi; sma[threadIdx.x >> 6] = ma; }
  __syncthreads();
  if (threadIdx.x == 0) {
    mi = fmaxf(fmaxf(smi[0], smi[1]), fmaxf(smi[2], smi[3]));
    ma = fmaxf(fmaxf(sma[0], sma[1]), fmaxf(sma[2], sma[3]));
    atomicMax(&stats[img * 2 + 0], __float_as_uint(mi));
    atomicMax(&stats[img * 2 + 1], __float_as_uint(ma));
  }
}

// kprod: product + inverse ROW FFT -> compact Y, reading the Hermitian half.
// 32 blocks/img; block g owns 16 mirror-closed rows:
//   g=0:  {0..7} U {505..511} U {256}   (stages rows 0..7, 504..511, 256)
//   g>=1: {8g..8g+7} U {505-8g..512-8g}
// X[q][r] for q>=257 reconstructed as conj(T[mirror-slot][512-q]).
__global__ __launch_bounds__(256) void kprod_kernel(
    const float2* __restrict__ XH, const float2* __restrict__ B2,
    const float* __restrict__ FP, float2* __restrict__ Y,
    const unsigned* __restrict__ stats, const float2* __restrict__ twg,
    int bmode)
{
  __shared__ float twr[256], twi[256];
  __shared__ float2 T[17][257];
  { const float2 t = twg[threadIdx.x]; twr[threadIdx.x] = t.x; twi[threadIdx.x] = t.y; }
  const int img = blockIdx.x >> 5;
  const int g   = blockIdx.x & 31;
  const int tid = threadIdx.x;
  const float2* __restrict__ Xi = XH + (size_t)img * XST;
  const int base1 = 8 * g;
  const int base2 = (g == 0) ? 504 : (505 - 8 * g);
  for (int idx = tid; idx < 257 * 16; idx += 256) {
    const int c = idx >> 4, sub = idx & 15;
    const int row = (sub < 8) ? (base1 + (sub & 7)) : (base2 + (sub & 7));
    T[sub][c] = Xi[c * NN + row];
  }
  if (g == 0) {
    for (int c = tid; c < 257; c += 256) T[16][c] = Xi[c * NN + 256];
  }
  bool fire = false;
  if (bmode == 0) {
    const float m1 = __uint_as_float(stats[img * 2 + 0]);
    const float m2 = __uint_as_float(stats[img * 2 + 1]);
    const double MTHR =
        961.0 * (log2(31.0) + log2(31.0)) * 1.1920928955078125e-7;
    fire = ((double)__fdiv_rn(m1, m2) <= MTHR);
  }
  __syncthreads();
  const int w = tid >> 6, lane = tid & 63;
  for (int t = 0; t < 4; ++t) {
    const int oi = w + 4 * t;
    int r, slot_r, slot_m;
    if (g == 0) {
      if (oi < 8)       { r = oi;       slot_r = oi;     slot_m = (oi == 0) ? 0 : (16 - oi); }
      else if (oi < 15) { r = 497 + oi; slot_r = oi + 1; slot_m = 15 - oi; }
      else              { r = 256;      slot_r = 16;     slot_m = 16; }
    } else {
      r = (oi < 8) ? (base1 + oi) : (base2 + (oi - 8));
      slot_r = oi;
      slot_m = 15 - oi;
    }
    float vr[8], vi[8];
    if (bmode) {
      const float2* __restrict__ Lrow = B2 + img * NPIX + r * NN;
#pragma unroll
      for (int e = 0; e < 8; ++e) {
        const int q = brev9(lane * 8 + e);
        float2 xb;
        if (q <= 256) xb = T[slot_r][q];
        else { const float2 tt = T[slot_m][512 - q]; xb = make_float2(tt.x, -tt.y); }
        const float2 l = Lrow[q];
        vr[e] = __fadd_rn(__fmul_rn(l.x, xb.x), __fmul_rn(l.y, xb.y));
        vi[e] = __fsub_rn(__fmul_rn(l.x, xb.y), __fmul_rn(l.y, xb.x));
      }
    } else {
      const float* __restrict__ Frow = FP + img * NPIX + r * NN;
#pragma unroll
      for (int e = 0; e < 8; ++e) {
        const int q = brev9(lane * 8 + e);
        float2 xb;
        if (q <= 256) xb = T[slot_r][q];
        else { const float2 tt = T[slot_m][512 - q]; xb = make_float2(tt.x, -tt.y); }
        const float fi = fire ? 0.f : xb.y;
        const float F  = Frow[q];
        vr[e] = __fmul_rn(F, xb.x);
        vi[e] = __fmul_rn(F, fi);
      }
    }
    fft512_core(vr, vi, 1, twr, twi, lane);
#pragma unroll
    for (int e = 0; e < 8; ++e) {
      const int c2 = lane * 8 + e;
      if (c2 >= 497 || c2 <= 15) {
        const int v = (c2 + 15) & 511;
        Y[(img * 31 + v) * NN + r] = make_float2(vr[e], vi[e]);
      }
    }
  }
}

// kA: 372 inverse col FFTs (compact Y) -> yv[img][961] (real part of crop).
__global__ __launch_bounds__(256) void kA_kernel(
    const float2* __restrict__ Y, float* __restrict__ yv,
    const float2* __restrict__ twg)
{
  __shared__ float twr[256], twi[256];
  { const float2 t = twg[threadIdx.x]; twr[threadIdx.x] = t.x; twi[threadIdx.x] = t.y; }
  __syncthreads();
  const int wid = blockIdx.x * 4 + (threadIdx.x >> 6);
  if (wid >= NIMG * 31) return;
  const int lane = threadIdx.x & 63;
  const int img = wid / 31, v = wid - img * 31;
  const float2* __restrict__ Yv = Y + (img * 31 + v) * NN;
  float vr[8], vi[8];
#pragma unroll
  for (int e = 0; e < 8; ++e) {
    const float2 z = Yv[brev9(lane * 8 + e)];
    vr[e] = z.x; vi[e] = z.y;
  }
  fft512_core(vr, vi, 1, twr, twi, lane);
#pragma unroll
  for (int e = 0; e < 8; ++e) {
    const int q2 = lane * 8 + e;
    const int u = (q2 + 15) & 511;
    if (u < 31) yv[img * 961 + u * 31 + v] = vr[e];
  }
}

// kC: CG scalar math (frozen ops) + next-p forward row FFTs + epilogue.
__global__ __launch_bounds__(1024) void kC_kernel(
    const float* __restrict__ yv, float2* __restrict__ R,
    float* __restrict__ bvec, float* __restrict__ xv,
    float* __restrict__ rv, float* __restrict__ pv,
    float* __restrict__ rsoldg, unsigned* __restrict__ stats,
    const float2* __restrict__ twg, float* __restrict__ out,
    int mode, int fin)
{
  __shared__ float twr[256], twi[256];
  __shared__ float pl[961], prodl[961];
  __shared__ float pwl[8], redf[16];
  __shared__ float scal;
  const int tid = threadIdx.x;
  const int wave = tid >> 6, lane = tid & 63;
  const int img = blockIdx.x;
  if (tid < 256) { const float2 t = twg[tid]; twr[tid] = t.x; twi[tid] = t.y; }
  __syncthreads();

  const bool act = tid < 961;
  const int g = img * 961 + tid;

  auto pairwise = [&]() -> float {
    __syncthreads();
    if (tid < 8) pwl[tid] = np_pw_base(prodl + tid * 120, (tid == 7) ? 121 : 120);
    __syncthreads();
    if (tid == 0) {
      const float L = __fadd_rn(__fadd_rn(pwl[0], pwl[1]), __fadd_rn(pwl[2], pwl[3]));
      const float Rr = __fadd_rn(__fadd_rn(pwl[4], pwl[5]), __fadd_rn(pwl[6], pwl[7]));
      scal = __fadd_rn(L, Rr);
    }
    __syncthreads();
    const float s = scal;
    __syncthreads();
    return s;
  };

  if (mode == 2) {
    if (act) {
      bvec[g] = yv[g];
      xv[g] = (float)(1.0 / 961.0);
      pl[tid] = (float)(1.0 / 961.0);
    }
  } else if (mode == 0) {
    if (act) {
      const float Ap = __fadd_rn(yv[g], xv[g]);
      const float r0 = __fsub_rn(bvec[g], Ap);
      rv[g] = r0; pv[g] = r0; pl[tid] = r0;
      prodl[tid] = __fmul_rn(r0, r0);
    }
    const float s = pairwise();
    if (tid == 0) rsoldg[img] = s;
  } else {
    float p = 0.f, Ap = 0.f, nr = 0.f;
    if (act) {
      p = pv[g];
      Ap = __fadd_rn(yv[g], p);
      prodl[tid] = __fmul_rn(p, Ap);
    }
    const float pAp = pairwise();
    if (tid == 0) scal = rsoldg[img] / pAp;
    __syncthreads();
    const float alpha = scal;
    __syncthreads();
    if (act) {
      xv[g] = __fadd_rn(xv[g], __fmul_rn(alpha, p));
      nr = __fsub_rn(rv[g], __fmul_rn(alpha, Ap));
      rv[g] = nr;
      prodl[tid] = __fmul_rn(nr, nr);
    }
    const float rsnew = pairwise();
    if (tid == 0) { scal = rsnew / rsoldg[img]; rsoldg[img] = rsnew; }
    __syncthreads();
    const float beta = scal;
    __syncthreads();
    if (act) {
      const float pn = __fadd_rn(nr, __fmul_rn(beta, p));
      pv[g] = pn; pl[tid] = pn;
    }
  }
  if (tid == 0) { stats[img * 2 + 0] = 0u; stats[img * 2 + 1] = 0u; }
  __syncthreads();

  if (fin) {
    const float x = act ? xv[g] : -3.4e38f;
    float v = x;
#pragma unroll
    for (int off = 32; off; off >>= 1) v = fmaxf(v, __shfl_xor(v, off));
    if (lane == 0) redf[wave] = v;
    __syncthreads();
    if (tid == 0) {
      float s = redf[0];
      for (int w2 = 1; w2 < 16; ++w2) s = fmaxf(s, redf[w2]);
      scal = s;
    }
    __syncthreads();
    const float maxv = scal;
    const float thrf = __fmul_rn(0.05f, maxv);
    float vvv = act ? x : 0.f;
    if (vvv < thrf) vvv = 0.f;
    if (vvv < 0.f)  vvv = 0.f;
    if (act) prodl[tid] = vvv;
    const float ssum = pairwise();
    if (act) out[g] = vvv / ssum;
    return;
  }

  for (int rep = 0; rep < 2; ++rep) {
    const int k = wave + 16 * rep;
    if (k < 31) {
      float vr[8], vi[8];
#pragma unroll
      for (int e = 0; e < 8; ++e) {
        const int q = brev9(lane * 8 + e);
        const int l = (q + 15) & 511;
        vr[e] = (l < 31) ? pl[k * 31 + l] : 0.f;
        vi[e] = 0.f;
      }
      fft512_core(vr, vi, 0, twr, twi, lane);
      float2* __restrict__ Rk = R + (img * 31 + k) * NN + lane * 8;
#pragma unroll
      for (int e = 0; e < 8; ++e) Rk[e] = make_float2(vr[e], vi[e]);
    }
  }
}

// ---------------------------------------------------------------------------
extern "C" void kernel_launch(void* const* d_in, const int* in_sizes, int n_in,
                              void* d_out, int out_size, void* d_ws, size_t ws_size,
                              hipStream_t stream)
{
  const float* bx = (const float*)d_in[0];
  const float* by = (const float*)d_in[1];
  const float* lx = (const float*)d_in[2];
  const float* ly = (const float*)d_in[3];

  // ws: B1 25.2 | B2 25.2 | XH 12.6 | R 1.5 | Y 1.5 | FP 12.6 | vecs (~79 MB)
  float* ws = (float*)d_ws;
  float2* B1 = (float2*)ws;
  float2* B2 = B1 + (size_t)NIMG * NPIX;
  float2* XH = B2 + (size_t)NIMG * NPIX;
  float2* R  = XH + (size_t)NIMG * XST;
  float2* Y  = R  + (size_t)NIMG * 31 * NN;
  float*  FP = (float*)(Y + (size_t)NIMG * 31 * NN);
  float*  vec = FP + (size_t)NIMG * NPIX;
  float*  bvec = vec;
  float*  xv   = bvec + NIMG * 961;
  float*  rv   = xv   + NIMG * 961;
  float*  pv   = rv   + NIMG * 961;
  float*  yv   = pv   + NIMG * 961;
  float*  rsold = yv  + NIMG * 961;
  unsigned* stats = (unsigned*)(rsold + NIMG);
  float2* twg = (float2*)(stats + 24);
  float* out = (float*)d_out;

  twiddle_kernel<<<1, 256, 0, stream>>>(twg);
  loadmag_kernel<<<NIMG * NPIX / 256, 256, 0, stream>>>(bx, by, lx, ly, B2, B1);
  rowfft_kernel<<<2 * NIMG * NN / 4, 256, 0, stream>>>(B2, B1, twg);
  colA_kernel<<<NIMG * 128, 256, 0, stream>>>(B2, twg);
  colB_kernel<<<NIMG * 65, 256, 0, stream>>>(B1, XH, twg);
  fp_kernel<<<NIMG * NPIX / 256, 256, 0, stream>>>(B2, FP);
  kprod_kernel<<<NIMG * 32, 256, 0, stream>>>(XH, B2, FP, Y, stats, twg, 1);
  kA_kernel<<<(NIMG * 31 + 3) / 4, 256, 0, stream>>>(Y, yv, twg);
  kC_kernel<<<NIMG, 1024, 0, stream>>>(yv, R, bvec, xv, rv, pv, rsold, stats,
                                       twg, out, 2, 0);

  for (int a = 0; a < 11; ++a) {
    kb_kernel<<<NIMG * 65, 256, 0, stream>>>(R, XH, stats, twg);
    kprod_kernel<<<NIMG * 32, 256, 0, stream>>>(XH, B2, FP, Y, stats, twg, 0);
    kA_kernel<<<(NIMG * 31 + 3) / 4, 256, 0, stream>>>(Y, yv, twg);
    const int mode = (a == 0) ? 0 : 1;
    const int fin  = (a == 10) ? 1 : 0;
    kC_kernel<<<NIMG, 1024, 0, stream>>>(yv, R, bvec, xv, rv, pv, rsold, stats,
                                         twg, out, mode, fin);
  }
}

// Round 17
// 1372.410 us; speedup vs baseline: 1.0835x; 1.0835x over previous
//
#include <hip/hip_runtime.h>
#include <math.h>

#define NIMG 12
#define NN 512
#define NPIX (NN * NN)
#define XST (257 * 512)   // compact Hermitian-half X: cols 0..256, 512 rows

__device__ __forceinline__ int brev9(int p) {
  return (int)(__brev((unsigned)p) >> 23);
}

// ---------------------------------------------------------------------------
// FROZEN 512-pt radix-2 DIT FFT core (f32, no FMA) — bit-identical to R11-R16.
// ---------------------------------------------------------------------------
__device__ __forceinline__ void fft512_core(
    float vr[8], float vi[8], const int inv,
    const float* __restrict__ twr, const float* __restrict__ twi,
    const int lane)
{
#pragma unroll
  for (int s = 0; s < 3; ++s) {
    const int half = 1 << s;
#pragma unroll
    for (int e = 0; e < 8; ++e) {
      if ((e & half) == 0) {
        const int j = (e & (half - 1)) << (8 - s);
        const float wr = twr[j];
        const float wi = inv ? -twi[j] : twi[j];
        const float br = vr[e + half], bi = vi[e + half];
        const float tr = __fsub_rn(__fmul_rn(wr, br), __fmul_rn(wi, bi));
        const float ti = __fadd_rn(__fmul_rn(wr, bi), __fmul_rn(wi, br));
        vr[e + half] = __fsub_rn(vr[e], tr); vi[e + half] = __fsub_rn(vi[e], ti);
        vr[e] = __fadd_rn(vr[e], tr); vi[e] = __fadd_rn(vi[e], ti);
      }
    }
  }
#pragma unroll
  for (int s = 3; s <= 8; ++s) {
    const int xm = 1 << (s - 3);
    const bool low = (lane & xm) == 0;
#pragma unroll
    for (int e = 0; e < 8; ++e) {
      const float orr = __shfl_xor(vr[e], xm);
      const float oii = __shfl_xor(vi[e], xm);
      const int j = ((((lane & (xm - 1)) << 3) | e)) << (8 - s);
      const float wr = twr[j];
      const float wi = inv ? -twi[j] : twi[j];
      if (low) {
        const float tr = __fsub_rn(__fmul_rn(wr, orr), __fmul_rn(wi, oii));
        const float ti = __fadd_rn(__fmul_rn(wr, oii), __fmul_rn(wi, orr));
        vr[e] = __fadd_rn(vr[e], tr); vi[e] = __fadd_rn(vi[e], ti);
      } else {
        const float tr = __fsub_rn(__fmul_rn(wr, vr[e]), __fmul_rn(wi, vi[e]));
        const float ti = __fadd_rn(__fmul_rn(wr, vi[e]), __fmul_rn(wi, vr[e]));
        vr[e] = __fsub_rn(orr, tr); vi[e] = __fsub_rn(oii, ti);
      }
    }
  }
  if (inv) {
    const float sc = 1.0f / 512.0f;
#pragma unroll
    for (int e = 0; e < 8; ++e) {
      vr[e] = __fmul_rn(vr[e], sc); vi[e] = __fmul_rn(vi[e], sc);
    }
  }
}

// numpy pairwise base block (frozen).
__device__ __forceinline__ float np_pw_base(const float* a, int n)
{
  float r0 = a[0], r1 = a[1], r2 = a[2], r3 = a[3];
  float r4 = a[4], r5 = a[5], r6 = a[6], r7 = a[7];
  int i = 8;
  const int lim = n - (n & 7);
  for (; i < lim; i += 8) {
    r0 = __fadd_rn(r0, a[i + 0]); r1 = __fadd_rn(r1, a[i + 1]);
    r2 = __fadd_rn(r2, a[i + 2]); r3 = __fadd_rn(r3, a[i + 3]);
    r4 = __fadd_rn(r4, a[i + 4]); r5 = __fadd_rn(r5, a[i + 5]);
    r6 = __fadd_rn(r6, a[i + 6]); r7 = __fadd_rn(r7, a[i + 7]);
  }
  float res = __fadd_rn(
      __fadd_rn(__fadd_rn(r0, r1), __fadd_rn(r2, r3)),
      __fadd_rn(__fadd_rn(r4, r5), __fadd_rn(r6, r7)));
  for (; i < n; ++i) res = __fadd_rn(res, a[i]);
  return res;
}

// ---------------------------------------------------------------------------
__global__ __launch_bounds__(256) void twiddle_kernel(float2* __restrict__ twg)
{
  const int k = threadIdx.x;
  double s, c;
  sincos(-2.0 * M_PI * (double)k / 512.0, &s, &c);
  twg[k] = make_float2((float)c, (float)s);
}

__global__ __launch_bounds__(256) void loadmag_kernel(
    const float* __restrict__ bx, const float* __restrict__ by,
    const float* __restrict__ lx, const float* __restrict__ ly,
    float2* __restrict__ B2, float2* __restrict__ B1)
{
  const int i = blockIdx.x * 256 + threadIdx.x;
  {
    const float a = lx[i], b = ly[i];
    const float s = __fadd_rn(__fmul_rn(a, a), __fmul_rn(b, b));
    B2[i] = make_float2((float)sqrt((double)s), 0.f);
  }
  {
    const float a = bx[i], b = by[i];
    const float s = __fadd_rn(__fmul_rn(a, a), __fmul_rn(b, b));
    B1[i] = make_float2((float)sqrt((double)s), 0.f);
  }
}

__global__ __launch_bounds__(256) void rowfft_kernel(
    float2* __restrict__ A, float2* __restrict__ B,
    const float2* __restrict__ twg)
{
  __shared__ float twr[256], twi[256];
  { const float2 t = twg[threadIdx.x]; twr[threadIdx.x] = t.x; twi[threadIdx.x] = t.y; }
  __syncthreads();
  int wid = blockIdx.x * 4 + (threadIdx.x >> 6);
  const int lane = threadIdx.x & 63;
  float2* buf = A;
  if (wid >= NIMG * NN) { wid -= NIMG * NN; buf = B; }
  const int base = (wid >> 9) * NPIX + (wid & 511) * NN;
  float vr[8], vi[8];
#pragma unroll
  for (int e = 0; e < 8; ++e) {
    const float2 z = buf[base + brev9(lane * 8 + e)];
    vr[e] = z.x; vi[e] = z.y;
  }
  fft512_core(vr, vi, 0, twr, twi, lane);
#pragma unroll
  for (int e = 0; e < 8; ++e)
    buf[base + lane * 8 + e] = make_float2(vr[e], vi[e]);
}

__global__ __launch_bounds__(256) void colA_kernel(
    float2* __restrict__ B2, const float2* __restrict__ twg)
{
  __shared__ float twr[256], twi[256];
  __shared__ float2 ld[4][520];
  { const float2 t = twg[threadIdx.x]; twr[threadIdx.x] = t.x; twi[threadIdx.x] = t.y; }
  const int img = blockIdx.x >> 7;
  const int c0  = (blockIdx.x & 127) * 4;
  const int tid = threadIdx.x;
  float2* __restrict__ base = B2 + img * NPIX;
  for (int it = 0; it < 8; ++it) {
    const int idx = it * 256 + tid;
    ld[idx & 3][idx >> 2] = base[(idx >> 2) * NN + c0 + (idx & 3)];
  }
  __syncthreads();
  const int w = tid >> 6, lane = tid & 63;
  float vr[8], vi[8];
#pragma unroll
  for (int e = 0; e < 8; ++e) {
    const float2 z = ld[w][brev9(lane * 8 + e)];
    vr[e] = z.x; vi[e] = z.y;
  }
  fft512_core(vr, vi, 0, twr, twi, lane);
#pragma unroll
  for (int e = 0; e < 8; ++e) ld[w][lane * 8 + e] = make_float2(vr[e], vi[e]);
  __syncthreads();
  for (int it = 0; it < 8; ++it) {
    const int idx = it * 256 + tid;
    base[(idx >> 2) * NN + c0 + (idx & 3)] = ld[idx & 3][idx >> 2];
  }
}

// colB: blur col FFTs, COMPACT Hermitian half: cols 0..256 -> XH [c][r].
__global__ __launch_bounds__(256) void colB_kernel(
    const float2* __restrict__ B1, float2* __restrict__ XH,
    const float2* __restrict__ twg)
{
  __shared__ float twr[256], twi[256];
  __shared__ float2 ld[4][520];
  { const float2 t = twg[threadIdx.x]; twr[threadIdx.x] = t.x; twi[threadIdx.x] = t.y; }
  const int img = blockIdx.x / 65;
  const int c0  = (blockIdx.x % 65) * 4;
  const int tid = threadIdx.x;
  const float2* __restrict__ in = B1 + img * NPIX;
  for (int it = 0; it < 8; ++it) {
    const int idx = it * 256 + tid;
    const int cc = c0 + (idx & 3);
    ld[idx & 3][idx >> 2] = in[(idx >> 2) * NN + (cc < NN ? cc : NN - 1)];
  }
  __syncthreads();
  const int w = tid >> 6, lane = tid & 63;
  const int c = c0 + w;
  if (c > 256) return;
  float vr[8], vi[8];
#pragma unroll
  for (int e = 0; e < 8; ++e) {
    const float2 z = ld[w][brev9(lane * 8 + e)];
    vr[e] = z.x; vi[e] = z.y;
  }
  fft512_core(vr, vi, 0, twr, twi, lane);
  float2* __restrict__ out = XH + (size_t)img * XST + c * NN + lane * 8;
#pragma unroll
  for (int e = 0; e < 8; ++e) out[e] = make_float2(vr[e], vi[e]);
}

__global__ __launch_bounds__(256) void fp_kernel(
    const float2* __restrict__ B2, float* __restrict__ FP)
{
  const int i = blockIdx.x * 256 + threadIdx.x;
  const float2 l = B2[i];
  FP[i] = __fadd_rn(__fmul_rn(l.x, l.x), __fmul_rn(l.y, l.y));
}

// kb: APPLY col-FFTs, compact half (cols 0..256) from R; fused mask stats.
__global__ __launch_bounds__(256) void kb_kernel(
    const float2* __restrict__ R, float2* __restrict__ XH,
    unsigned* __restrict__ stats, const float2* __restrict__ twg)
{
  __shared__ float twr[256], twi[256];
  __shared__ float smi[4], sma[4];
  { const float2 t = twg[threadIdx.x]; twr[threadIdx.x] = t.x; twi[threadIdx.x] = t.y; }
  __syncthreads();
  const int img = blockIdx.x / 65;
  const int c   = (blockIdx.x % 65) * 4 + (threadIdx.x >> 6);
  const int lane = threadIdx.x & 63;
  float mi = 0.f, ma = 0.f;
  if (c <= 256) {
    float vr[8], vi[8];
#pragma unroll
    for (int e = 0; e < 8; ++e) {
      const int q = brev9(lane * 8 + e);
      const int k = (q + 15) & 511;
      if (k < 31) {
        const float2 z = R[(img * 31 + k) * NN + c];
        vr[e] = z.x; vi[e] = z.y;
      } else { vr[e] = 0.f; vi[e] = 0.f; }
    }
    fft512_core(vr, vi, 0, twr, twi, lane);
#pragma unroll
    for (int e = 0; e < 8; ++e) {
      mi = fmaxf(mi, fabsf(vi[e]));
      const float ab = (float)sqrt(
          (double)__fadd_rn(__fmul_rn(vr[e], vr[e]), __fmul_rn(vi[e], vi[e])));
      ma = fmaxf(ma, ab);
    }
    float2* __restrict__ out = XH + (size_t)img * XST + c * NN + lane * 8;
#pragma unroll
    for (int e = 0; e < 8; ++e) out[e] = make_float2(vr[e], vi[e]);
  }
#pragma unroll
  for (int off = 32; off; off >>= 1) {
    mi = fmaxf(mi, __shfl_xor(mi, off));
    ma = fmaxf(ma, __shfl_xor(ma, off));
  }
  if (lane == 0) { smi[threadIdx.x >> 6] = mi; sma[threadIdx.x >> 6] = ma; }
  __syncthreads();
  if (threadIdx.x == 0) {
    mi = fmaxf(fmaxf(smi[0], smi[1]), fmaxf(smi[2], smi[3]));
    ma = fmaxf(fmaxf(sma[0], sma[1]), fmaxf(sma[2], sma[3]));
    atomicMax(&stats[img * 2 + 0], __float_as_uint(mi));
    atomicMax(&stats[img * 2 + 1], __float_as_uint(ma));
  }
}

// kprod: product + inverse ROW FFT -> compact Y, Hermitian-half read.
// 64 blocks/img (restores 3 blocks/CU); block g owns 8 mirror-closed rows:
//   g=0:  slots {0,1,2,3} = rows 0..3; slots {4,5,6} = rows 509..511; slot 7 = 256
//   g>=1: slots 0..3 = rows 4g..4g+3; slots 4..7 = rows 505+s-4g
// mirror slot: g=0: {0,6,5,4,3,2,1,7}; g>=1: 7-s.
// X[q][r] for q>=257 reconstructed as conj(T[mirror][512-q]).
__global__ __launch_bounds__(256) void kprod_kernel(
    const float2* __restrict__ XH, const float2* __restrict__ B2,
    const float* __restrict__ FP, float2* __restrict__ Y,
    const unsigned* __restrict__ stats, const float2* __restrict__ twg,
    int bmode)
{
  __shared__ float twr[256], twi[256];
  __shared__ float2 T[8][257];
  { const float2 t = twg[threadIdx.x]; twr[threadIdx.x] = t.x; twi[threadIdx.x] = t.y; }
  const int img = blockIdx.x >> 6;
  const int g   = blockIdx.x & 63;
  const int tid = threadIdx.x;
  const float2* __restrict__ Xi = XH + (size_t)img * XST;
  for (int idx = tid; idx < 257 * 8; idx += 256) {
    const int c = idx >> 3, sub = idx & 7;
    int row;
    if (g == 0) row = (sub < 4) ? sub : ((sub < 7) ? (505 + sub) : 256);
    else        row = (sub < 4) ? (4 * g + sub) : (505 + sub - 4 * g);
    T[sub][c] = Xi[c * NN + row];
  }
  bool fire = false;
  if (bmode == 0) {
    const float m1 = __uint_as_float(stats[img * 2 + 0]);
    const float m2 = __uint_as_float(stats[img * 2 + 1]);
    const double MTHR =
        961.0 * (log2(31.0) + log2(31.0)) * 1.1920928955078125e-7;
    fire = ((double)__fdiv_rn(m1, m2) <= MTHR);
  }
  __syncthreads();
  const int w = tid >> 6, lane = tid & 63;
  for (int t = 0; t < 2; ++t) {
    const int oi = w + 4 * t;          // slot of this output row
    int r, slot_m;
    if (g == 0) {
      const int mir0[8] = {0, 6, 5, 4, 3, 2, 1, 7};
      r = (oi < 4) ? oi : ((oi < 7) ? (505 + oi) : 256);
      slot_m = mir0[oi];
    } else {
      r = (oi < 4) ? (4 * g + oi) : (505 + oi - 4 * g);
      slot_m = 7 - oi;
    }
    float vr[8], vi[8];
    if (bmode) {
      const float2* __restrict__ Lrow = B2 + img * NPIX + r * NN;
#pragma unroll
      for (int e = 0; e < 8; ++e) {
        const int q = brev9(lane * 8 + e);
        float2 xb;
        if (q <= 256) xb = T[oi][q];
        else { const float2 tt = T[slot_m][512 - q]; xb = make_float2(tt.x, -tt.y); }
        const float2 l = Lrow[q];
        vr[e] = __fadd_rn(__fmul_rn(l.x, xb.x), __fmul_rn(l.y, xb.y));
        vi[e] = __fsub_rn(__fmul_rn(l.x, xb.y), __fmul_rn(l.y, xb.x));
      }
    } else {
      const float* __restrict__ Frow = FP + img * NPIX + r * NN;
#pragma unroll
      for (int e = 0; e < 8; ++e) {
        const int q = brev9(lane * 8 + e);
        float2 xb;
        if (q <= 256) xb = T[oi][q];
        else { const float2 tt = T[slot_m][512 - q]; xb = make_float2(tt.x, -tt.y); }
        const float fi = fire ? 0.f : xb.y;
        const float F  = Frow[q];
        vr[e] = __fmul_rn(F, xb.x);
        vi[e] = __fmul_rn(F, fi);
      }
    }
    fft512_core(vr, vi, 1, twr, twi, lane);
#pragma unroll
    for (int e = 0; e < 8; ++e) {
      const int c2 = lane * 8 + e;
      if (c2 >= 497 || c2 <= 15) {
        const int v = (c2 + 15) & 511;
        Y[(img * 31 + v) * NN + r] = make_float2(vr[e], vi[e]);
      }
    }
  }
}

// kA: 372 inverse col FFTs (compact Y) -> yv[img][961] (real part of crop).
__global__ __launch_bounds__(256) void kA_kernel(
    const float2* __restrict__ Y, float* __restrict__ yv,
    const float2* __restrict__ twg)
{
  __shared__ float twr[256], twi[256];
  { const float2 t = twg[threadIdx.x]; twr[threadIdx.x] = t.x; twi[threadIdx.x] = t.y; }
  __syncthreads();
  const int wid = blockIdx.x * 4 + (threadIdx.x >> 6);
  if (wid >= NIMG * 31) return;
  const int lane = threadIdx.x & 63;
  const int img = wid / 31, v = wid - img * 31;
  const float2* __restrict__ Yv = Y + (img * 31 + v) * NN;
  float vr[8], vi[8];
#pragma unroll
  for (int e = 0; e < 8; ++e) {
    const float2 z = Yv[brev9(lane * 8 + e)];
    vr[e] = z.x; vi[e] = z.y;
  }
  fft512_core(vr, vi, 1, twr, twi, lane);
#pragma unroll
  for (int e = 0; e < 8; ++e) {
    const int q2 = lane * 8 + e;
    const int u = (q2 + 15) & 511;
    if (u < 31) yv[img * 961 + u * 31 + v] = vr[e];
  }
}

// kC: CG scalar math (frozen ops) + next-p forward row FFTs + epilogue.
__global__ __launch_bounds__(1024) void kC_kernel(
    const float* __restrict__ yv, float2* __restrict__ R,
    float* __restrict__ bvec, float* __restrict__ xv,
    float* __restrict__ rv, float* __restrict__ pv,
    float* __restrict__ rsoldg, unsigned* __restrict__ stats,
    const float2* __restrict__ twg, float* __restrict__ out,
    int mode, int fin)
{
  __shared__ float twr[256], twi[256];
  __shared__ float pl[961], prodl[961];
  __shared__ float pwl[8], redf[16];
  __shared__ float scal;
  const int tid = threadIdx.x;
  const int wave = tid >> 6, lane = tid & 63;
  const int img = blockIdx.x;
  if (tid < 256) { const float2 t = twg[tid]; twr[tid] = t.x; twi[tid] = t.y; }
  __syncthreads();

  const bool act = tid < 961;
  const int g = img * 961 + tid;

  auto pairwise = [&]() -> float {
    __syncthreads();
    if (tid < 8) pwl[tid] = np_pw_base(prodl + tid * 120, (tid == 7) ? 121 : 120);
    __syncthreads();
    if (tid == 0) {
      const float L = __fadd_rn(__fadd_rn(pwl[0], pwl[1]), __fadd_rn(pwl[2], pwl[3]));
      const float Rr = __fadd_rn(__fadd_rn(pwl[4], pwl[5]), __fadd_rn(pwl[6], pwl[7]));
      scal = __fadd_rn(L, Rr);
    }
    __syncthreads();
    const float s = scal;
    __syncthreads();
    return s;
  };

  if (mode == 2) {
    if (act) {
      bvec[g] = yv[g];
      xv[g] = (float)(1.0 / 961.0);
      pl[tid] = (float)(1.0 / 961.0);
    }
  } else if (mode == 0) {
    if (act) {
      const float Ap = __fadd_rn(yv[g], xv[g]);
      const float r0 = __fsub_rn(bvec[g], Ap);
      rv[g] = r0; pv[g] = r0; pl[tid] = r0;
      prodl[tid] = __fmul_rn(r0, r0);
    }
    const float s = pairwise();
    if (tid == 0) rsoldg[img] = s;
  } else {
    float p = 0.f, Ap = 0.f, nr = 0.f;
    if (act) {
      p = pv[g];
      Ap = __fadd_rn(yv[g], p);
      prodl[tid] = __fmul_rn(p, Ap);
    }
    const float pAp = pairwise();
    if (tid == 0) scal = rsoldg[img] / pAp;
    __syncthreads();
    const float alpha = scal;
    __syncthreads();
    if (act) {
      xv[g] = __fadd_rn(xv[g], __fmul_rn(alpha, p));
      nr = __fsub_rn(rv[g], __fmul_rn(alpha, Ap));
      rv[g] = nr;
      prodl[tid] = __fmul_rn(nr, nr);
    }
    const float rsnew = pairwise();
    if (tid == 0) { scal = rsnew / rsoldg[img]; rsoldg[img] = rsnew; }
    __syncthreads();
    const float beta = scal;
    __syncthreads();
    if (act) {
      const float pn = __fadd_rn(nr, __fmul_rn(beta, p));
      pv[g] = pn; pl[tid] = pn;
    }
  }
  if (tid == 0) { stats[img * 2 + 0] = 0u; stats[img * 2 + 1] = 0u; }
  __syncthreads();

  if (fin) {
    const float x = act ? xv[g] : -3.4e38f;
    float v = x;
#pragma unroll
    for (int off = 32; off; off >>= 1) v = fmaxf(v, __shfl_xor(v, off));
    if (lane == 0) redf[wave] = v;
    __syncthreads();
    if (tid == 0) {
      float s = redf[0];
      for (int w2 = 1; w2 < 16; ++w2) s = fmaxf(s, redf[w2]);
      scal = s;
    }
    __syncthreads();
    const float maxv = scal;
    const float thrf = __fmul_rn(0.05f, maxv);
    float vvv = act ? x : 0.f;
    if (vvv < thrf) vvv = 0.f;
    if (vvv < 0.f)  vvv = 0.f;
    if (act) prodl[tid] = vvv;
    const float ssum = pairwise();
    if (act) out[g] = vvv / ssum;
    return;
  }

  for (int rep = 0; rep < 2; ++rep) {
    const int k = wave + 16 * rep;
    if (k < 31) {
      float vr[8], vi[8];
#pragma unroll
      for (int e = 0; e < 8; ++e) {
        const int q = brev9(lane * 8 + e);
        const int l = (q + 15) & 511;
        vr[e] = (l < 31) ? pl[k * 31 + l] : 0.f;
        vi[e] = 0.f;
      }
      fft512_core(vr, vi, 0, twr, twi, lane);
      float2* __restrict__ Rk = R + (img * 31 + k) * NN + lane * 8;
#pragma unroll
      for (int e = 0; e < 8; ++e) Rk[e] = make_float2(vr[e], vi[e]);
    }
  }
}

// ---------------------------------------------------------------------------
extern "C" void kernel_launch(void* const* d_in, const int* in_sizes, int n_in,
                              void* d_out, int out_size, void* d_ws, size_t ws_size,
                              hipStream_t stream)
{
  const float* bx = (const float*)d_in[0];
  const float* by = (const float*)d_in[1];
  const float* lx = (const float*)d_in[2];
  const float* ly = (const float*)d_in[3];

  // ws: B1 25.2 | B2 25.2 | XH 12.6 | R 1.5 | Y 1.5 | FP 12.6 | vecs (~79 MB)
  float* ws = (float*)d_ws;
  float2* B1 = (float2*)ws;
  float2* B2 = B1 + (size_t)NIMG * NPIX;
  float2* XH = B2 + (size_t)NIMG * NPIX;
  float2* R  = XH + (size_t)NIMG * XST;
  float2* Y  = R  + (size_t)NIMG * 31 * NN;
  float*  FP = (float*)(Y + (size_t)NIMG * 31 * NN);
  float*  vec = FP + (size_t)NIMG * NPIX;
  float*  bvec = vec;
  float*  xv   = bvec + NIMG * 961;
  float*  rv   = xv   + NIMG * 961;
  float*  pv   = rv   + NIMG * 961;
  float*  yv   = pv   + NIMG * 961;
  float*  rsold = yv  + NIMG * 961;
  unsigned* stats = (unsigned*)(rsold + NIMG);
  float2* twg = (float2*)(stats + 24);
  float* out = (float*)d_out;

  twiddle_kernel<<<1, 256, 0, stream>>>(twg);
  loadmag_kernel<<<NIMG * NPIX / 256, 256, 0, stream>>>(bx, by, lx, ly, B2, B1);
  rowfft_kernel<<<2 * NIMG * NN / 4, 256, 0, stream>>>(B2, B1, twg);
  colA_kernel<<<NIMG * 128, 256, 0, stream>>>(B2, twg);
  colB_kernel<<<NIMG * 65, 256, 0, stream>>>(B1, XH, twg);
  fp_kernel<<<NIMG * NPIX / 256, 256, 0, stream>>>(B2, FP);
  kprod_kernel<<<NIMG * 64, 256, 0, stream>>>(XH, B2, FP, Y, stats, twg, 1);
  kA_kernel<<<(NIMG * 31 + 3) / 4, 256, 0, stream>>>(Y, yv, twg);
  kC_kernel<<<NIMG, 1024, 0, stream>>>(yv, R, bvec, xv, rv, pv, rsold, stats,
                                       twg, out, 2, 0);

  for (int a = 0; a < 11; ++a) {
    kb_kernel<<<NIMG * 65, 256, 0, stream>>>(R, XH, stats, twg);
    kprod_kernel<<<NIMG * 64, 256, 0, stream>>>(XH, B2, FP, Y, stats, twg, 0);
    kA_kernel<<<(NIMG * 31 + 3) / 4, 256, 0, stream>>>(Y, yv, twg);
    const int mode = (a == 0) ? 0 : 1;
    const int fin  = (a == 10) ? 1 : 0;
    kC_kernel<<<NIMG, 1024, 0, stream>>>(yv, R, bvec, xv, rv, pv, rsold, stats,
                                         twg, out, mode, fin);
  }
}